// Round 8
// baseline (58.753 us; speedup 1.0000x reference)
//
#include <hip/hip_runtime.h>
#include <hip/hip_bf16.h>

// Attention: out[b,q,v] = softmax_d( Q[q,:]·K[b,d,:] / sqrt(128) ) · V[b,d,v]
// B=32, D=8192, DK=DV=128. fp32 in/out, bf16 MFMA internally.
// R7: 8 waves/block (512 thr), key-split: wave (kh,w) does key-half kh of
//     each 64-tile x v-cols [32w,32w+32). Same HBM traffic as R4/R6, but
//     16 waves/CU (4/SIMD) with per-wave regs ~halved. Epilogue merges the
//     two key-halves (m/l/O) via LDS.

#define NSPLIT 16
#define Dseq 8192
#define Dk 128
#define KT 64
#define NT (Dseq / NSPLIT / KT)   // 8 iters per block

typedef __attribute__((ext_vector_type(8))) short bf16x8;
typedef __attribute__((ext_vector_type(16))) float f32x16;

__device__ __forceinline__ unsigned cvt_pk(float lo, float hi) {
  unsigned d;
  asm("v_cvt_pk_bf16_f32 %0, %1, %2" : "=v"(d) : "v"(lo), "v"(hi));
  return d;
}
__device__ __forceinline__ void plane32_swap(unsigned& a, unsigned& b) {
  // out a = {a.lo, b.lo}, out b = {a.hi, b.hi} across lane<32/lane>=32
  asm volatile("v_permlane32_swap_b32 %0, %1" : "+v"(a), "+v"(b));
}

union frag_u { unsigned u[4]; bf16x8 v; };

// mfma_f32_32x32x16_bf16 layouts (m74/m101 verified):
//  A[32,16]: lane l -> row = l&31, k = (l>>5)*8 + j
//  B[16,32]: lane l -> col = l&31, k = (l>>5)*8 + j
//  C/D     : lane l -> col = l&31, row = (r&3) + 8*(r>>2) + 4*(l>>5)

__global__ __launch_bounds__(512, 4) void attn_partial(
    const float* __restrict__ Q, const float* __restrict__ K,
    const float* __restrict__ V, float* __restrict__ ows,
    float* __restrict__ mws, float* __restrict__ lws) {
  // 32 KB: K bf16 double buffer (2 x 64 rows x 256B). Epilogue O-merge tile
  // [4][32][33] f32 (16.9 KB) and transpose tile overlay it.
  __shared__ alignas(16) char smem[2 * KT * 256];
  __shared__ float m_lds[2][32];
  __shared__ float l_lds[2][32];
  char* kls = smem;

  const int tid = threadIdx.x;
  const int lane = tid & 63;
  const int wv = tid >> 6;         // wave 0..7
  const int w = wv & 3;            // v-col group: cols [32w, 32w+32)
  const int kh = wv >> 2;          // key-half of each 64-tile
  const int c32 = lane & 31;
  const int hi = lane >> 5;
  const int wg = blockIdx.x;
  const int b = wg >> 4;           // NSPLIT=16
  const int kb0 = (wg & 15) * (Dseq / NSPLIT);

  const float scale = 0.088388347648318447f;  // 1/sqrt(128)

  // K staging geometry: wave wv owns tile rows [8wv, 8wv+8); lane covers
  // row 8wv+(lane>>3), f32 cols (lane&7)*16 .. +15.
  const int krow_l = 8 * wv + (lane >> 3);
  const int kcol0 = (lane & 7) * 16;
  const int ksw = (krow_l & 7) << 4;                  // write-side XOR
  const int ko0 = krow_l * 256 + (lane & 7) * 32;     // tile-local byte

  // ---- Q as B-fragment (q = c32, k = hi*8 + j + 16s), prescaled, resident
  bf16x8 qa[8];
  {
    const float* qrow = Q + c32 * Dk + hi * 8;
#pragma unroll
    for (int s = 0; s < 8; ++s) {
      float4 a = *(const float4*)(qrow + s * 16);
      float4 b4 = *(const float4*)(qrow + s * 16 + 4);
      frag_u f;
      f.u[0] = cvt_pk(a.x * scale, a.y * scale);
      f.u[1] = cvt_pk(a.z * scale, a.w * scale);
      f.u[2] = cvt_pk(b4.x * scale, b4.y * scale);
      f.u[3] = cvt_pk(b4.z * scale, b4.w * scale);
      qa[s] = f.v;
    }
  }

  const float* Kb = K + (size_t)b * Dseq * Dk;
  const float* Vb = V + (size_t)b * Dseq * Dk;

  f32x16 acc;
#pragma unroll
  for (int r = 0; r < 16; ++r) acc[r] = 0.0f;
  float m_r = -1e30f, l_r = 0.0f;

  // ---- prologue: stage K tile 0 into buf 0 (bf16, swizzled)
  {
    const float* src = Kb + (size_t)(kb0 + krow_l) * Dk + kcol0;
    float4 k0 = *(const float4*)(src);
    float4 k1 = *(const float4*)(src + 4);
    float4 k2 = *(const float4*)(src + 8);
    float4 k3 = *(const float4*)(src + 12);
    frag_u lo, hi4;
    lo.u[0] = cvt_pk(k0.x, k0.y);  lo.u[1] = cvt_pk(k0.z, k0.w);
    lo.u[2] = cvt_pk(k1.x, k1.y);  lo.u[3] = cvt_pk(k1.z, k1.w);
    hi4.u[0] = cvt_pk(k2.x, k2.y); hi4.u[1] = cvt_pk(k2.z, k2.w);
    hi4.u[2] = cvt_pk(k3.x, k3.y); hi4.u[3] = cvt_pk(k3.z, k3.w);
    *(bf16x8*)(kls + (ko0 ^ ksw)) = lo.v;
    *(bf16x8*)(kls + ((ko0 + 16) ^ ksw)) = hi4.v;
  }
  __syncthreads();

  for (int t = 0; t < NT; ++t) {
    const int kb = kb0 + t * KT;

    // A) issue V(t) loads (unique: wave's 32 v-cols x its 32 keys, 4KB)
    float vr[16];
    {
      const float* vsrc = Vb + (size_t)(kb + 32 * kh + hi * 8) * Dk + 32 * w + c32;
#pragma unroll
      for (int s2 = 0; s2 < 2; ++s2)
#pragma unroll
        for (int j = 0; j < 8; ++j)
          vr[s2 * 8 + j] = vsrc[(size_t)(16 * s2 + j) * Dk];
    }

    // B) issue K(t+1) loads (cooperative: wave's 8 rows, 4KB)
    float4 kr0, kr1, kr2, kr3;
    if (t + 1 < NT) {
      const float* src = Kb + (size_t)(kb + KT + krow_l) * Dk + kcol0;
      kr0 = *(const float4*)(src);
      kr1 = *(const float4*)(src + 4);
      kr2 = *(const float4*)(src + 8);
      kr3 = *(const float4*)(src + 12);
    }
    __builtin_amdgcn_sched_barrier(0);  // keep load issues above compute

    // C) K fragments from LDS buf[t&1]: wave's keys = rows 32kh + c32
    const char* kbase = kls + (t & 1) * 16384;
    bf16x8 kf[8];
#pragma unroll
    for (int s = 0; s < 8; ++s) {
      const int o = ((32 * kh + c32) * 256 + hi * 16 + s * 32) ^ ((c32 & 7) << 4);
      kf[s] = *(const bf16x8*)(kbase + o);
    }

    // D) S^T[key,q] = mfma(A=K, B=Q): lane q=c32, regs = keys crow(r,hi)
    f32x16 S;
#pragma unroll
    for (int r = 0; r < 16; ++r) S[r] = 0.0f;
#pragma unroll
    for (int s = 0; s < 8; ++s)
      S = __builtin_amdgcn_mfma_f32_32x32x16_bf16(kf[s], qa[s], S, 0, 0, 0);

    // E) online softmax over wave's 32 keys (per-lane q; xor32 joins hi halves)
    float tmax = S[0];
#pragma unroll
    for (int r = 1; r < 16; ++r) tmax = fmaxf(tmax, S[r]);
    tmax = fmaxf(tmax, __shfl_xor(tmax, 32, 64));
    const float mn = fmaxf(m_r, tmax);
    const float sf = __expf(m_r - mn);
    m_r = mn;
    float p[16];
#pragma unroll
    for (int r = 0; r < 16; ++r) p[r] = __expf(S[r] - mn);
    float rs = p[0];
#pragma unroll
    for (int r = 1; r < 16; ++r) rs += p[r];
    rs += __shfl_xor(rs, 32, 64);
    l_r = l_r * sf + rs;
#pragma unroll
    for (int r = 0; r < 16; ++r) acc[r] *= sf;

    // F) P^T -> 2 B-fragments via cvt_pk + permlane32_swap
    unsigned a0 = cvt_pk(p[0], p[1]),   a1 = cvt_pk(p[2], p[3]);
    unsigned a2 = cvt_pk(p[4], p[5]),   a3 = cvt_pk(p[6], p[7]);
    unsigned a4 = cvt_pk(p[8], p[9]),   a5 = cvt_pk(p[10], p[11]);
    unsigned a6 = cvt_pk(p[12], p[13]), a7 = cvt_pk(p[14], p[15]);
    plane32_swap(a0, a2);
    plane32_swap(a1, a3);
    plane32_swap(a4, a6);
    plane32_swap(a5, a7);
    frag_u pa0, pa1;
    pa0.u[0] = a0; pa0.u[1] = a1; pa0.u[2] = a2; pa0.u[3] = a3;
    pa1.u[0] = a4; pa1.u[1] = a5; pa1.u[2] = a6; pa1.u[3] = a7;

    // G) V fragments from prefetched regs; O^T += mfma(A=V^T, B=P^T) x2
    frag_u vf0, vf1;
    vf0.u[0] = cvt_pk(vr[0], vr[1]);   vf0.u[1] = cvt_pk(vr[2], vr[3]);
    vf0.u[2] = cvt_pk(vr[4], vr[5]);   vf0.u[3] = cvt_pk(vr[6], vr[7]);
    vf1.u[0] = cvt_pk(vr[8], vr[9]);   vf1.u[1] = cvt_pk(vr[10], vr[11]);
    vf1.u[2] = cvt_pk(vr[12], vr[13]); vf1.u[3] = cvt_pk(vr[14], vr[15]);
    acc = __builtin_amdgcn_mfma_f32_32x32x16_bf16(vf0.v, pa0.v, acc, 0, 0, 0);
    acc = __builtin_amdgcn_mfma_f32_32x32x16_bf16(vf1.v, pa1.v, acc, 0, 0, 0);

    // H) stage K(t+1) into buf[(t+1)&1]
    if (t + 1 < NT) {
      frag_u lo, hi4;
      lo.u[0] = cvt_pk(kr0.x, kr0.y);  lo.u[1] = cvt_pk(kr0.z, kr0.w);
      lo.u[2] = cvt_pk(kr1.x, kr1.y);  lo.u[3] = cvt_pk(kr1.z, kr1.w);
      hi4.u[0] = cvt_pk(kr2.x, kr2.y); hi4.u[1] = cvt_pk(kr2.z, kr2.w);
      hi4.u[2] = cvt_pk(kr3.x, kr3.y); hi4.u[3] = cvt_pk(kr3.z, kr3.w);
      char* wbase = kls + ((t + 1) & 1) * 16384;
      *(bf16x8*)(wbase + (ko0 ^ ksw)) = lo.v;
      *(bf16x8*)(wbase + ((ko0 + 16) ^ ksw)) = hi4.v;
    }
    __syncthreads();
  }

  // ---- epilogue: merge key-halves, transpose, store partial
  if (w == 0) {                       // waves 0 and 4 hold the two (m,l) sets
    m_lds[kh][c32] = m_r;             // hi=0/1 write identical values (benign)
    l_lds[kh][c32] = l_r;
  }
  __syncthreads();

  const float M = fmaxf(m_lds[0][c32], m_lds[1][c32]);
  const float fw = __expf(m_r - M);
#pragma unroll
  for (int r = 0; r < 16; ++r) acc[r] *= fw;

  float* og = (float*)smem;           // [4][32][33] f32 (16.9 KB, overlays K)
  if (kh == 1) {
#pragma unroll
    for (int r = 0; r < 16; ++r) {
      const int vloc = (r & 3) + 8 * (r >> 2) + 4 * hi;
      og[(w * 32 + vloc) * 33 + c32] = acc[r];
    }
  }
  __syncthreads();
  float* ol = (float*)smem;           // [128][33], same layout/indices as og
  if (kh == 0) {
#pragma unroll
    for (int r = 0; r < 16; ++r) {
      const int vloc = (r & 3) + 8 * (r >> 2) + 4 * hi;
      const int idx = (w * 32 + vloc) * 33 + c32;
      ol[idx] = acc[r] + og[idx];     // read-then-write same slot, same thread
    }
  }
  __syncthreads();
  {
    float* oo = ows + (size_t)wg * 4096;
    const int q = tid >> 4;           // 0..31
    const int v0 = (tid & 15) * 8;    // 0..120
#pragma unroll
    for (int g = 0; g < 2; ++g) {
      float4 s;
      s.x = ol[(v0 + 4 * g + 0) * 33 + q];
      s.y = ol[(v0 + 4 * g + 1) * 33 + q];
      s.z = ol[(v0 + 4 * g + 2) * 33 + q];
      s.w = ol[(v0 + 4 * g + 3) * 33 + q];
      *(float4*)(oo + q * 128 + v0 + 4 * g) = s;
    }
  }
  if (wv == 0 && hi == 0) {
    const float L = l_lds[0][c32] * __expf(m_lds[0][c32] - M) +
                    l_lds[1][c32] * __expf(m_lds[1][c32] - M);
    mws[wg * 32 + c32] = M;
    lws[wg * 32 + c32] = L;
  }
}

// Combine NSPLIT partials per (b, q) row.
__global__ void attn_combine(const float* __restrict__ ows,
                             const float* __restrict__ mws,
                             const float* __restrict__ lws,
                             float* __restrict__ out) {
  const int bq = blockIdx.x;       // b*32 + q
  const int v = threadIdx.x;       // 0..127
  const int b = bq >> 5;
  const int qrow = bq & 31;
  const int slot0 = b * NSPLIT;

  float M = -1e30f;
#pragma unroll
  for (int c = 0; c < NSPLIT; ++c)
    M = fmaxf(M, mws[(slot0 + c) * 32 + qrow]);

  float acc = 0.0f, L = 0.0f;
#pragma unroll
  for (int c = 0; c < NSPLIT; ++c) {
    const float f = __expf(mws[(slot0 + c) * 32 + qrow] - M);
    L += lws[(slot0 + c) * 32 + qrow] * f;
    acc += f * ows[(size_t)(slot0 + c) * 4096 + qrow * 128 + v];
  }
  out[(size_t)bq * 128 + v] = acc / L;
}

extern "C" void kernel_launch(void* const* d_in, const int* in_sizes, int n_in,
                              void* d_out, int out_size, void* d_ws, size_t ws_size,
                              hipStream_t stream) {
  const float* Q = (const float*)d_in[0];
  const float* K = (const float*)d_in[1];
  const float* V = (const float*)d_in[2];
  float* out = (float*)d_out;

  float* ows = (float*)d_ws;                        // 512 * 4096 f32 = 8 MB
  float* mws = ows + (size_t)32 * NSPLIT * 4096;    // 512 * 32 f32
  float* lws = mws + (size_t)32 * NSPLIT * 32;      // 512 * 32 f32

  attn_partial<<<32 * NSPLIT, 512, 0, stream>>>(Q, K, V, ows, mws, lws);
  attn_combine<<<32 * 32, 128, 0, stream>>>(ows, mws, lws, out);
}